// Round 1
// baseline (34.468 us; speedup 1.0000x reference)
//
#include <hip/hip_runtime.h>
#include <hip/hip_bf16.h>

// Monomials x^lx * y^ly * z^lz for lx+ly+lz <= 3, K=20, in the module's
// recursive enumeration order:
//  k: 0:(0,0,0) 1:(1,0,0) 2:(0,1,0) 3:(0,0,1)
//     4:(2,0,0) 5:(1,1,0) 6:(1,0,1) 7:(0,2,0) 8:(0,1,1) 9:(0,0,2)
//    10:(3,0,0) 11:(2,1,0) 12:(2,0,1) 13:(1,2,0) 14:(1,1,1)
//    15:(1,0,2) 16:(0,3,0) 17:(0,2,1) 18:(0,1,2) 19:(0,0,3)
//
// Output [N,20] f32 row-major. One thread handles 4 consecutive outputs
// (one float4 quad); 5 quads per point. Stores are perfectly coalesced
// 16B/lane. Inputs re-read 5x but L1-broadcast (input is 24MB vs 160MB out).

__global__ void angular_monomials_kernel(const float* __restrict__ vec,
                                         float* __restrict__ out,
                                         int n_points) {
    const int total_quads = n_points * 5;  // 10M for N=2e6, fits int32
    const int stride = gridDim.x * blockDim.x;
    for (int j = blockIdx.x * blockDim.x + threadIdx.x; j < total_quads; j += stride) {
        const int i = j / 5;       // point index (magic-mul divide)
        const int t = j - i * 5;   // quad index 0..4

        const float x = vec[i * 3 + 0];
        const float y = vec[i * 3 + 1];
        const float z = vec[i * 3 + 2];

        float4 o;
        switch (t) {
            case 0:  // 1, x, y, z
                o = make_float4(1.0f, x, y, z);
                break;
            case 1: {  // x^2, xy, xz, y^2
                o = make_float4(x * x, x * y, x * z, y * y);
                break;
            }
            case 2: {  // yz, z^2, x^3, x^2 y
                const float xx = x * x;
                o = make_float4(y * z, z * z, xx * x, xx * y);
                break;
            }
            case 3: {  // x^2 z, x y^2, xyz, x z^2
                const float xy = x * y;
                o = make_float4(x * x * z, xy * y, xy * z, x * (z * z));
                break;
            }
            default: {  // y^3, y^2 z, y z^2, z^3
                const float yy = y * y;
                const float zz = z * z;
                o = make_float4(yy * y, yy * z, y * zz, zz * z);
                break;
            }
        }
        reinterpret_cast<float4*>(out)[j] = o;
    }
}

extern "C" void kernel_launch(void* const* d_in, const int* in_sizes, int n_in,
                              void* d_out, int out_size, void* d_ws, size_t ws_size,
                              hipStream_t stream) {
    const float* vec = (const float*)d_in[0];
    float* out = (float*)d_out;
    const int n_points = in_sizes[0] / 3;

    const int total_quads = n_points * 5;
    const int block = 256;
    int grid = (total_quads + block - 1) / block;
    if (grid > 2048) grid = 2048;  // grid-stride; ~8 blocks/CU on 256 CUs

    angular_monomials_kernel<<<grid, block, 0, stream>>>(vec, out, n_points);
}

// Round 3
// 32.741 us; speedup vs baseline: 1.0527x; 1.0527x over previous
//
#include <hip/hip_runtime.h>
#include <hip/hip_bf16.h>

// Monomials x^lx * y^ly * z^lz for lx+ly+lz <= 3, K=20, in the module's
// recursive enumeration order:
//  k: 0:(0,0,0) 1:(1,0,0) 2:(0,1,0) 3:(0,0,1)
//     4:(2,0,0) 5:(1,1,0) 6:(1,0,1) 7:(0,2,0) 8:(0,1,1) 9:(0,0,2)
//    10:(3,0,0) 11:(2,1,0) 12:(2,0,1) 13:(1,2,0) 14:(1,1,1)
//    15:(1,0,2) 16:(0,3,0) 17:(0,2,1) 18:(0,1,2) 19:(0,0,3)
//
// Output [N,20] f32 row-major. One thread handles 4 consecutive outputs
// (one quad); 5 quads per point. Stores are perfectly coalesced 16B/lane
// and NONTEMPORAL (write-once data; keep L2 free for the input so the
// 5x-redundant point reads stay L2-resident). Native clang vector type
// used because __builtin_nontemporal_store rejects HIP_vector_type.

typedef float f32x4 __attribute__((ext_vector_type(4)));

__global__ void angular_monomials_kernel(const float* __restrict__ vec,
                                         float* __restrict__ out,
                                         int n_points) {
    const int total_quads = n_points * 5;  // 10M for N=2e6, fits int32
    const int stride = gridDim.x * blockDim.x;
    for (int j = blockIdx.x * blockDim.x + threadIdx.x; j < total_quads; j += stride) {
        const int i = j / 5;       // point index (magic-mul divide)
        const int t = j - i * 5;   // quad index 0..4

        const float x = vec[i * 3 + 0];
        const float y = vec[i * 3 + 1];
        const float z = vec[i * 3 + 2];

        f32x4 o;
        switch (t) {
            case 0:  // 1, x, y, z
                o = (f32x4){1.0f, x, y, z};
                break;
            case 1: {  // x^2, xy, xz, y^2
                o = (f32x4){x * x, x * y, x * z, y * y};
                break;
            }
            case 2: {  // yz, z^2, x^3, x^2 y
                const float xx = x * x;
                o = (f32x4){y * z, z * z, xx * x, xx * y};
                break;
            }
            case 3: {  // x^2 z, x y^2, xyz, x z^2
                const float xy = x * y;
                o = (f32x4){x * x * z, xy * y, xy * z, x * (z * z)};
                break;
            }
            default: {  // y^3, y^2 z, y z^2, z^3
                const float yy = y * y;
                const float zz = z * z;
                o = (f32x4){yy * y, yy * z, y * zz, zz * z};
                break;
            }
        }
        __builtin_nontemporal_store(o, reinterpret_cast<f32x4*>(out) + j);
    }
}

extern "C" void kernel_launch(void* const* d_in, const int* in_sizes, int n_in,
                              void* d_out, int out_size, void* d_ws, size_t ws_size,
                              hipStream_t stream) {
    const float* vec = (const float*)d_in[0];
    float* out = (float*)d_out;
    const int n_points = in_sizes[0] / 3;

    const int total_quads = n_points * 5;
    const int block = 256;
    int grid = (total_quads + block - 1) / block;
    if (grid > 2048) grid = 2048;  // grid-stride; 8 blocks/CU x 4 waves = full occupancy

    angular_monomials_kernel<<<grid, block, 0, stream>>>(vec, out, n_points);
}

// Round 4
// 29.843 us; speedup vs baseline: 1.1550x; 1.0971x over previous
//
#include <hip/hip_runtime.h>
#include <hip/hip_bf16.h>

// Monomials x^lx * y^ly * z^lz for lx+ly+lz <= 3, K=20, in the module's
// recursive enumeration order:
//  k: 0:(0,0,0) 1:(1,0,0) 2:(0,1,0) 3:(0,0,1)
//     4:(2,0,0) 5:(1,1,0) 6:(1,0,1) 7:(0,2,0) 8:(0,1,1) 9:(0,0,2)
//    10:(3,0,0) 11:(2,1,0) 12:(2,0,1) 13:(1,2,0) 14:(1,1,1)
//    15:(1,0,2) 16:(0,3,0) 17:(0,2,1) 18:(0,1,2) 19:(0,0,3)
//
// Output [N,20] f32 row-major. One thread per quad of 4 consecutive outputs;
// 5 quads per point. Loop-free exact-grid launch: one straight-line
// load -> compute -> nontemporal dwordx4 store per thread. Stores perfectly
// coalesced 16B/lane; NT keeps the write-once 160MB output out of L2.

typedef float f32x4 __attribute__((ext_vector_type(4)));

__global__ void __launch_bounds__(256)
angular_monomials_kernel(const float* __restrict__ vec,
                         float* __restrict__ out,
                         int total_quads) {
    const int j = blockIdx.x * 256 + threadIdx.x;
    if (j >= total_quads) return;

    const int i = j / 5;       // point index (magic-mul divide)
    const int t = j - i * 5;   // quad index 0..4

    const float x = vec[i * 3 + 0];
    const float y = vec[i * 3 + 1];
    const float z = vec[i * 3 + 2];

    f32x4 o;
    switch (t) {
        case 0:  // 1, x, y, z
            o = (f32x4){1.0f, x, y, z};
            break;
        case 1: {  // x^2, xy, xz, y^2
            o = (f32x4){x * x, x * y, x * z, y * y};
            break;
        }
        case 2: {  // yz, z^2, x^3, x^2 y
            const float xx = x * x;
            o = (f32x4){y * z, z * z, xx * x, xx * y};
            break;
        }
        case 3: {  // x^2 z, x y^2, xyz, x z^2
            const float xy = x * y;
            o = (f32x4){x * x * z, xy * y, xy * z, x * (z * z)};
            break;
        }
        default: {  // y^3, y^2 z, y z^2, z^3
            const float yy = y * y;
            const float zz = z * z;
            o = (f32x4){yy * y, yy * z, y * zz, zz * z};
            break;
        }
    }
    __builtin_nontemporal_store(o, reinterpret_cast<f32x4*>(out) + j);
}

extern "C" void kernel_launch(void* const* d_in, const int* in_sizes, int n_in,
                              void* d_out, int out_size, void* d_ws, size_t ws_size,
                              hipStream_t stream) {
    const float* vec = (const float*)d_in[0];
    float* out = (float*)d_out;
    const int n_points = in_sizes[0] / 3;

    const int total_quads = n_points * 5;
    const int block = 256;
    const int grid = (total_quads + block - 1) / block;  // exact, no loop

    angular_monomials_kernel<<<grid, block, 0, stream>>>(vec, out, total_quads);
}